// Round 4
// baseline (259.480 us; speedup 1.0000x reference)
//
#include <hip/hip_runtime.h>
#include <math.h>

#define NB 32
#define NN 512
#define ROWC 2048ull

typedef __attribute__((ext_vector_type(8))) short bf16x8;
typedef __attribute__((ext_vector_type(4))) float f32x4;

__device__ __forceinline__ unsigned int fbits(float f) {
  union { float f; unsigned int u; } v; v.f = f; return v.u;
}
__device__ __forceinline__ float bcast(unsigned int u) {
  union { unsigned int u; float f; } v; v.u = u; return v.f;
}
// round-to-nearest-even bf16, returned in low 16 bits
__device__ __forceinline__ unsigned int bf16_rne(float f) {
  unsigned int b = fbits(f);
  return (b + 0x7FFFu + ((b >> 16) & 1u)) >> 16;
}

// XCD-aware block decode: flat id -> (tile_x, tile_y, batch) such that all
// 16 tiles of a batch land on ONE XCD (dispatch round-robins id%8 -> XCD).
// 512 blocks = 8 XCD * 4 batches * 16 tiles. Bijection.
__device__ __forceinline__ void decode_block(int& bx, int& by, int& b) {
  int id = blockIdx.x;
  int xcd = id & 7;
  int slot = id >> 3;            // 0..63
  b = xcd * 4 + (slot >> 4);     // 4 batches per XCD
  int tile = slot & 15;
  bx = tile & 3;
  by = tile >> 2;
}

// Fragment-ordered LDS address for a 128(row)x64(k) bf16 tile.
// Region (khalf, blk) holds a 16x32 MFMA fragment: lane = (row&15)+16*k8,
// element j = k&7 at +j*2. XOR swizzle on byte[6:4] keeps staged writes
// conflict-free; reads are a bijection within each 1KB region.
__device__ __forceinline__ int frag_byte(int blk, int lane, int khalf) {
  int base = ((((khalf << 3) + blk) << 6) + lane) << 4;
  int swz = (blk ^ (lane >> 4) ^ (khalf << 2)) & 7;
  return base ^ (swz << 4);
}

// Stage a 128x64 fp32 tile (row-major, k contiguous) as bf16 hi/lo pair.
__device__ __forceinline__ void stage_hilo(const float* __restrict__ src, int row0, int k0,
                                           char* __restrict__ Lh, char* __restrict__ Ll,
                                           int t) {
#pragma unroll
  for (int i = 0; i < 8; ++i) {
    int idx = i * 256 + t;        // 0..2047 float4 units
    int r = idx >> 4, c4 = idx & 15;
    int k = c4 << 2;
    float4 f = *(const float4*)&src[(size_t)(row0 + r) * NN + k0 + k];
    unsigned int b0 = fbits(f.x), b1 = fbits(f.y), b2 = fbits(f.z), b3 = fbits(f.w);
    unsigned int h01 = (b0 >> 16) | (b1 & 0xFFFF0000u);
    unsigned int h23 = (b2 >> 16) | (b3 & 0xFFFF0000u);
    float r0 = f.x - bcast(b0 & 0xFFFF0000u);
    float r1 = f.y - bcast(b1 & 0xFFFF0000u);
    float r2 = f.z - bcast(b2 & 0xFFFF0000u);
    float r3 = f.w - bcast(b3 & 0xFFFF0000u);
    unsigned int l01 = (fbits(r0) >> 16) | (fbits(r1) & 0xFFFF0000u);
    unsigned int l23 = (fbits(r2) >> 16) | (fbits(r3) & 0xFFFF0000u);
    int khalf = k >> 5, k8 = (k >> 3) & 3, j = k & 7;
    int byte = frag_byte(r >> 4, (r & 15) + (k8 << 4), khalf) + (j << 1);
    *(uint2*)(Lh + byte) = make_uint2(h01, h23);
    *(uint2*)(Ll + byte) = make_uint2(l01, l23);
  }
}

// --- Kernel 1: e = px.hx^T (split-bf16 MFMA) + masked row/col softmax stats -
__global__ __launch_bounds__(256) void gemm_e_stats(
    const float* __restrict__ px, const float* __restrict__ hx,
    const int* __restrict__ p_mask, const int* __restrict__ h_mask,
    float* __restrict__ e,
    float* __restrict__ rpm, float* __restrict__ rps,
    float* __restrict__ cpm, float* __restrict__ cps) {
  __shared__ char Ah[16384], Al[16384], Bh[16384], Bl[16384];
  __shared__ int pmk[128], hmk[128];
  __shared__ float st_m[2][128], st_s[2][128], sc_m[2][128], sc_s[2][128];
  int bxi, byi, b;
  decode_block(bxi, byi, b);
  const float* A = px + (size_t)b * NN * NN;
  const float* B = hx + (size_t)b * NN * NN;
  float* C = e + (size_t)b * NN * NN;
  const int row0 = byi * 128, col0 = bxi * 128;
  const int t = threadIdx.x;
  const int l = t & 63, w = t >> 6;
  const int wr = w >> 1, wc = w & 1;
  const int g = l >> 4, li = l & 15;

  if (t < 128) pmk[t] = p_mask[(size_t)b * NN + row0 + t];
  else hmk[t - 128] = h_mask[(size_t)b * NN + col0 + (t - 128)];

  f32x4 acc[4][4];
#pragma unroll
  for (int i = 0; i < 4; ++i)
#pragma unroll
    for (int j = 0; j < 4; ++j)
#pragma unroll
      for (int r = 0; r < 4; ++r) acc[i][j][r] = 0.f;

  for (int k0 = 0; k0 < NN; k0 += 64) {
    stage_hilo(A, row0, k0, Ah, Al, t);
    stage_hilo(B, col0, k0, Bh, Bl, t);
    __syncthreads();
#pragma unroll
    for (int kh = 0; kh < 2; ++kh) {
      bf16x8 ah[4], al[4], bh[4], bl[4];
#pragma unroll
      for (int i = 0; i < 4; ++i) {
        int ab = frag_byte(wr * 4 + i, l, kh);
        ah[i] = *(const bf16x8*)(Ah + ab);
        al[i] = *(const bf16x8*)(Al + ab);
        int bb = frag_byte(wc * 4 + i, l, kh);
        bh[i] = *(const bf16x8*)(Bh + bb);
        bl[i] = *(const bf16x8*)(Bl + bb);
      }
#pragma unroll
      for (int i = 0; i < 4; ++i)
#pragma unroll
        for (int j = 0; j < 4; ++j) {
          acc[i][j] = __builtin_amdgcn_mfma_f32_16x16x32_bf16(ah[i], bh[j], acc[i][j], 0, 0, 0);
          acc[i][j] = __builtin_amdgcn_mfma_f32_16x16x32_bf16(ah[i], bl[j], acc[i][j], 0, 0, 0);
          acc[i][j] = __builtin_amdgcn_mfma_f32_16x16x32_bf16(al[i], bh[j], acc[i][j], 0, 0, 0);
        }
    }
    __syncthreads();
  }

  // write e
#pragma unroll
  for (int i = 0; i < 4; ++i)
#pragma unroll
    for (int j = 0; j < 4; ++j)
#pragma unroll
      for (int r = 0; r < 4; ++r) {
        int row = row0 + wr * 64 + i * 16 + g * 4 + r;
        int col = col0 + wc * 64 + j * 16 + li;
        C[(size_t)row * NN + col] = acc[i][j][r];
      }

  // ---- row stats (softmax over h): max & sum(exp) over this block's 128 cols
#pragma unroll
  for (int i = 0; i < 4; ++i)
#pragma unroll
    for (int r = 0; r < 4; ++r) {
      float v[4];
      float m = -INFINITY;
#pragma unroll
      for (int j = 0; j < 4; ++j) {
        v[j] = hmk[wc * 64 + j * 16 + li] ? -INFINITY : acc[i][j][r];
        m = fmaxf(m, v[j]);
      }
#pragma unroll
      for (int o = 1; o < 16; o <<= 1) m = fmaxf(m, __shfl_xor(m, o));
      float s = 0.f;
#pragma unroll
      for (int j = 0; j < 4; ++j) s += (v[j] == -INFINITY) ? 0.f : __expf(v[j] - m);
#pragma unroll
      for (int o = 1; o < 16; o <<= 1) s += __shfl_xor(s, o);
      if (li == 0) {
        st_m[wc][wr * 64 + i * 16 + g * 4 + r] = m;
        st_s[wc][wr * 64 + i * 16 + g * 4 + r] = s;
      }
    }

  // ---- col stats (softmax over p): max & sum(exp) over this block's 128 rows
#pragma unroll
  for (int j = 0; j < 4; ++j) {
    float v[16];
    float m = -INFINITY;
#pragma unroll
    for (int i = 0; i < 4; ++i)
#pragma unroll
      for (int r = 0; r < 4; ++r) {
        float x = pmk[wr * 64 + i * 16 + g * 4 + r] ? -INFINITY : acc[i][j][r];
        v[i * 4 + r] = x;
        m = fmaxf(m, x);
      }
    m = fmaxf(m, __shfl_xor(m, 16));
    m = fmaxf(m, __shfl_xor(m, 32));
    float s = 0.f;
#pragma unroll
    for (int q = 0; q < 16; ++q) s += (v[q] == -INFINITY) ? 0.f : __expf(v[q] - m);
    s += __shfl_xor(s, 16);
    s += __shfl_xor(s, 32);
    if (g == 0) {
      sc_m[wr][wc * 64 + j * 16 + li] = m;
      sc_s[wr][wc * 64 + j * 16 + li] = s;
    }
  }
  __syncthreads();

  if (t < 128) {
    float m0 = st_m[0][t], m1 = st_m[1][t];
    float s0 = st_s[0][t], s1 = st_s[1][t];
    float m = fmaxf(m0, m1);
    float s = 0.f;
    if (s0 > 0.f) s += s0 * __expf(m0 - m);
    if (s1 > 0.f) s += s1 * __expf(m1 - m);
    rpm[((size_t)b * 4 + bxi) * NN + row0 + t] = m;
    rps[((size_t)b * 4 + bxi) * NN + row0 + t] = s;
  } else {
    int c = t - 128;
    float m0 = sc_m[0][c], m1 = sc_m[1][c];
    float s0 = sc_s[0][c], s1 = sc_s[1][c];
    float m = fmaxf(m0, m1);
    float s = 0.f;
    if (s0 > 0.f) s += s0 * __expf(m0 - m);
    if (s1 > 0.f) s += s1 * __expf(m1 - m);
    cpm[((size_t)b * 4 + byi) * NN + col0 + c] = m;
    cps[((size_t)b * 4 + byi) * NN + col0 + c] = s;
  }
}

// --- Kernel 2: merge 4 partials per row/col (online-softmax merge) ---------
__global__ __launch_bounds__(512) void merge_stats(
    const float* __restrict__ rpm, const float* __restrict__ rps,
    const float* __restrict__ cpm, const float* __restrict__ cps,
    float* __restrict__ rmax, float* __restrict__ rinv,
    float* __restrict__ cmax, float* __restrict__ cinv) {
  const int b = blockIdx.x;
  const int t = threadIdx.x;
  const float* pm = blockIdx.y == 0 ? rpm : cpm;
  const float* ps = blockIdx.y == 0 ? rps : cps;
  float* fm = blockIdx.y == 0 ? rmax : cmax;
  float* fi = blockIdx.y == 0 ? rinv : cinv;
  float mj[4], sj[4];
  float m = -INFINITY;
#pragma unroll
  for (int j = 0; j < 4; ++j) {
    mj[j] = pm[((size_t)b * 4 + j) * NN + t];
    sj[j] = ps[((size_t)b * 4 + j) * NN + t];
    m = fmaxf(m, mj[j]);
  }
  float s = 0.f;
#pragma unroll
  for (int j = 0; j < 4; ++j)
    if (sj[j] > 0.f) s += sj[j] * __expf(mj[j] - m);
  fm[(size_t)b * NN + t] = m;
  fi[(size_t)b * NN + t] = 1.0f / s;
}

// --- Kernel 3: m_p : px_hat = softmax_h(e) @ hx, weights computed on the fly
__global__ __launch_bounds__(256) void gemm_wp(
    const float* __restrict__ E, const float* __restrict__ hxg,
    const float* __restrict__ pxg, const int* __restrict__ h_mask,
    const float* __restrict__ rmax, const float* __restrict__ rinv,
    float* __restrict__ outg) {
  __shared__ union {
    struct { char A[16384]; char B[16384]; } s;
    float ep[64][132];
  } u;
  int bxi, byi, b;
  decode_block(bxi, byi, b);
  const float* Eb = E + (size_t)b * NN * NN;
  const float* B = hxg + (size_t)b * NN * NN;
  const float* X = pxg + (size_t)b * NN * NN;
  const int* hm = h_mask + (size_t)b * NN;
  const float* rmx = rmax + (size_t)b * NN;
  const float* rin = rinv + (size_t)b * NN;
  float* out = outg + (size_t)b * NN * ROWC;
  const int row0 = byi * 128, col0 = bxi * 128;
  const int t = threadIdx.x;
  const int l = t & 63, w = t >> 6;
  const int wr = w >> 1, wc = w & 1;

  float rmv[8];
#pragma unroll
  for (int i = 0; i < 8; ++i) rmv[i] = rmx[row0 + ((i * 256 + t) >> 4)];

  f32x4 acc[4][4];
#pragma unroll
  for (int i = 0; i < 4; ++i)
#pragma unroll
    for (int j = 0; j < 4; ++j)
#pragma unroll
      for (int r = 0; r < 4; ++r) acc[i][j][r] = 0.f;

  for (int k0 = 0; k0 < NN; k0 += 64) {
    // stage A: w = exp(e - rowmax), masked h -> 0, to bf16 frag order
#pragma unroll
    for (int i = 0; i < 8; ++i) {
      int idx = i * 256 + t;
      int r = idx >> 4, c4 = idx & 15, k = c4 << 2;
      float4 f = *(const float4*)&Eb[(size_t)(row0 + r) * NN + k0 + k];
      int4 m4 = *(const int4*)&hm[k0 + k];
      float w0 = m4.x ? 0.f : __expf(f.x - rmv[i]);
      float w1 = m4.y ? 0.f : __expf(f.y - rmv[i]);
      float w2 = m4.z ? 0.f : __expf(f.z - rmv[i]);
      float w3 = m4.w ? 0.f : __expf(f.w - rmv[i]);
      unsigned int p01 = bf16_rne(w0) | (bf16_rne(w1) << 16);
      unsigned int p23 = bf16_rne(w2) | (bf16_rne(w3) << 16);
      int khalf = k >> 5, k8 = (k >> 3) & 3, j = k & 7;
      int byte = frag_byte(r >> 4, (r & 15) + (k8 << 4), khalf) + (j << 1);
      *(uint2*)(u.s.A + byte) = make_uint2(p01, p23);
    }
    // stage B: hx fp32 [k][n] -> bf16, transposed into frag order (k-pairs)
#pragma unroll
    for (int i = 0; i < 4; ++i) {
      int idx = i * 256 + t;
      int kp = idx >> 5, nq = idx & 31;
      int k = kp << 1, n = nq << 2;
      const float* p0 = &B[(size_t)(k0 + k) * NN + col0 + n];
      float4 f0 = *(const float4*)p0;
      float4 f1 = *(const float4*)(p0 + NN);
      int khalf = k >> 5, k8 = (k >> 3) & 3, j = k & 7;
      float fa0[4] = {f0.x, f0.y, f0.z, f0.w};
      float fa1[4] = {f1.x, f1.y, f1.z, f1.w};
#pragma unroll
      for (int c = 0; c < 4; ++c) {
        unsigned int pk = bf16_rne(fa0[c]) | (bf16_rne(fa1[c]) << 16);
        int nn2 = n + c;
        int byte = frag_byte(nn2 >> 4, (nn2 & 15) + (k8 << 4), khalf) + (j << 1);
        *(unsigned int*)(u.s.B + byte) = pk;
      }
    }
    __syncthreads();
#pragma unroll
    for (int kh = 0; kh < 2; ++kh) {
      bf16x8 av[4], bv[4];
#pragma unroll
      for (int i = 0; i < 4; ++i) {
        av[i] = *(const bf16x8*)(u.s.A + frag_byte(wr * 4 + i, l, kh));
        bv[i] = *(const bf16x8*)(u.s.B + frag_byte(wc * 4 + i, l, kh));
      }
#pragma unroll
      for (int i = 0; i < 4; ++i)
#pragma unroll
        for (int j = 0; j < 4; ++j)
          acc[i][j] = __builtin_amdgcn_mfma_f32_16x16x32_bf16(av[i], bv[j], acc[i][j], 0, 0, 0);
    }
    __syncthreads();
  }

  const int g = l >> 4, li = l & 15;
#pragma unroll
  for (int pass = 0; pass < 2; ++pass) {
    if (wr == pass) {
#pragma unroll
      for (int i = 0; i < 4; ++i)
#pragma unroll
        for (int j = 0; j < 4; ++j)
#pragma unroll
          for (int r = 0; r < 4; ++r)
            u.ep[i * 16 + g * 4 + r][wc * 64 + j * 16 + li] = acc[i][j][r];
    }
    __syncthreads();
#pragma unroll
    for (int i = 0; i < 8; ++i) {
      int idx = i * 256 + t;
      int r = idx >> 5, c4 = idx & 31;
      int grow = row0 + pass * 64 + r;
      float ri = rin[grow];
      float4 ph = *(const float4*)&u.ep[r][c4 * 4];
      ph.x *= ri; ph.y *= ri; ph.z *= ri; ph.w *= ri;
      float4 xv = *(const float4*)&X[(size_t)grow * NN + col0 + c4 * 4];
      size_t base = (size_t)grow * ROWC + col0 + c4 * 4;
      *(float4*)&out[base] = xv;
      *(float4*)&out[base + 512] = ph;
      float4 df = {xv.x - ph.x, xv.y - ph.y, xv.z - ph.z, xv.w - ph.w};
      *(float4*)&out[base + 1024] = df;
      float4 pr = {xv.x * ph.x, xv.y * ph.y, xv.z * ph.z, xv.w * ph.w};
      *(float4*)&out[base + 1536] = pr;
    }
    __syncthreads();
  }
}

// --- Kernel 4: m_h : hx_hat = softmax_p(e)^T @ px, weights on the fly ------
__global__ __launch_bounds__(256) void gemm_wh(
    const float* __restrict__ E, const float* __restrict__ pxg,
    const float* __restrict__ hxg, const int* __restrict__ p_mask,
    const float* __restrict__ cmax, const float* __restrict__ cinv,
    float* __restrict__ outg) {
  __shared__ union {
    struct { char A[16384]; char B[16384]; } s;
    float ep[64][132];
  } u;
  int bxi, byi, b;
  decode_block(bxi, byi, b);
  const float* Eb = E + (size_t)b * NN * NN;
  const float* B = pxg + (size_t)b * NN * NN;
  const float* X = hxg + (size_t)b * NN * NN;
  const int* pmsk = p_mask + (size_t)b * NN;
  const float* cmx = cmax + (size_t)b * NN;
  const float* cin = cinv + (size_t)b * NN;
  float* out = outg + (size_t)b * NN * ROWC;
  const int row0 = byi * 128, col0 = bxi * 128;  // rows = h
  const int t = threadIdx.x;
  const int l = t & 63, w = t >> 6;
  const int wr = w >> 1, wc = w & 1;

  float4 cmv[4];
#pragma unroll
  for (int i = 0; i < 4; ++i) {
    int idx = i * 256 + t;
    int n = (idx & 31) << 2;
    cmv[i] = *(const float4*)&cmx[row0 + n];
  }

  f32x4 acc[4][4];
#pragma unroll
  for (int i = 0; i < 4; ++i)
#pragma unroll
    for (int j = 0; j < 4; ++j)
#pragma unroll
      for (int r = 0; r < 4; ++r) acc[i][j][r] = 0.f;

  for (int k0 = 0; k0 < NN; k0 += 64) {
    // stage A: w[h][p] = exp(e[p][h] - colmax[h]), masked p -> 0 (k-pairs)
#pragma unroll
    for (int i = 0; i < 4; ++i) {
      int idx = i * 256 + t;
      int kp = idx >> 5, nq = idx & 31;
      int k = kp << 1, n = nq << 2;
      const float* p0 = &Eb[(size_t)(k0 + k) * NN + row0 + n];
      float4 f0 = *(const float4*)p0;
      float4 f1 = *(const float4*)(p0 + NN);
      int pm0 = pmsk[k0 + k], pm1 = pmsk[k0 + k + 1];
      float fa0[4] = {f0.x, f0.y, f0.z, f0.w};
      float fa1[4] = {f1.x, f1.y, f1.z, f1.w};
      float cma[4] = {cmv[i].x, cmv[i].y, cmv[i].z, cmv[i].w};
      int khalf = k >> 5, k8 = (k >> 3) & 3, j = k & 7;
#pragma unroll
      for (int c = 0; c < 4; ++c) {
        float w0 = pm0 ? 0.f : __expf(fa0[c] - cma[c]);
        float w1 = pm1 ? 0.f : __expf(fa1[c] - cma[c]);
        unsigned int pk = bf16_rne(w0) | (bf16_rne(w1) << 16);
        int nn2 = n + c;
        int byte = frag_byte(nn2 >> 4, (nn2 & 15) + (k8 << 4), khalf) + (j << 1);
        *(unsigned int*)(u.s.A + byte) = pk;
      }
    }
    // stage B: px fp32 [k][n] -> bf16 frag order (k-pairs)
#pragma unroll
    for (int i = 0; i < 4; ++i) {
      int idx = i * 256 + t;
      int kp = idx >> 5, nq = idx & 31;
      int k = kp << 1, n = nq << 2;
      const float* p0 = &B[(size_t)(k0 + k) * NN + col0 + n];
      float4 f0 = *(const float4*)p0;
      float4 f1 = *(const float4*)(p0 + NN);
      int khalf = k >> 5, k8 = (k >> 3) & 3, j = k & 7;
      float fa0[4] = {f0.x, f0.y, f0.z, f0.w};
      float fa1[4] = {f1.x, f1.y, f1.z, f1.w};
#pragma unroll
      for (int c = 0; c < 4; ++c) {
        unsigned int pk = bf16_rne(fa0[c]) | (bf16_rne(fa1[c]) << 16);
        int nn2 = n + c;
        int byte = frag_byte(nn2 >> 4, (nn2 & 15) + (k8 << 4), khalf) + (j << 1);
        *(unsigned int*)(u.s.B + byte) = pk;
      }
    }
    __syncthreads();
#pragma unroll
    for (int kh = 0; kh < 2; ++kh) {
      bf16x8 av[4], bv[4];
#pragma unroll
      for (int i = 0; i < 4; ++i) {
        av[i] = *(const bf16x8*)(u.s.A + frag_byte(wr * 4 + i, l, kh));
        bv[i] = *(const bf16x8*)(u.s.B + frag_byte(wc * 4 + i, l, kh));
      }
#pragma unroll
      for (int i = 0; i < 4; ++i)
#pragma unroll
        for (int j = 0; j < 4; ++j)
          acc[i][j] = __builtin_amdgcn_mfma_f32_16x16x32_bf16(av[i], bv[j], acc[i][j], 0, 0, 0);
    }
    __syncthreads();
  }

  const int g = l >> 4, li = l & 15;
#pragma unroll
  for (int pass = 0; pass < 2; ++pass) {
    if (wr == pass) {
#pragma unroll
      for (int i = 0; i < 4; ++i)
#pragma unroll
        for (int j = 0; j < 4; ++j)
#pragma unroll
          for (int r = 0; r < 4; ++r)
            u.ep[i * 16 + g * 4 + r][wc * 64 + j * 16 + li] = acc[i][j][r];
    }
    __syncthreads();
#pragma unroll
    for (int i = 0; i < 8; ++i) {
      int idx = i * 256 + t;
      int r = idx >> 5, c4 = idx & 31;
      int grow = row0 + pass * 64 + r;  // h
      float ci = cin[grow];
      float4 hh = *(const float4*)&u.ep[r][c4 * 4];
      hh.x *= ci; hh.y *= ci; hh.z *= ci; hh.w *= ci;
      float4 xv = *(const float4*)&X[(size_t)grow * NN + col0 + c4 * 4];
      size_t base = (size_t)grow * ROWC + col0 + c4 * 4;
      *(float4*)&out[base] = xv;
      *(float4*)&out[base + 512] = hh;
      float4 df = {xv.x - hh.x, xv.y - hh.y, xv.z - hh.z, xv.w - hh.w};
      *(float4*)&out[base + 1024] = df;
      float4 pr = {xv.x * hh.x, xv.y * hh.y, xv.z * hh.z, xv.w * hh.w};
      *(float4*)&out[base + 1536] = pr;
    }
    __syncthreads();
  }
}

extern "C" void kernel_launch(void* const* d_in, const int* in_sizes, int n_in,
                              void* d_out, int out_size, void* d_ws, size_t ws_size,
                              hipStream_t stream) {
  const float* px = (const float*)d_in[0];
  const float* hx = (const float*)d_in[1];
  const int* p_mask = (const int*)d_in[2];
  const int* h_mask = (const int*)d_in[3];
  float* out = (float*)d_out;

  float* E = (float*)d_ws;                         // 33.5 MB fp32
  float* rpm = E + (size_t)NB * NN * NN;           // [B][4][NN] partial row max
  float* rps = rpm + (size_t)NB * 4 * NN;
  float* cpm = rps + (size_t)NB * 4 * NN;
  float* cps = cpm + (size_t)NB * 4 * NN;
  float* rmaxv = cps + (size_t)NB * 4 * NN;        // [B][NN] finals
  float* rinvv = rmaxv + (size_t)NB * NN;
  float* cmaxv = rinvv + (size_t)NB * NN;
  float* cinvv = cmaxv + (size_t)NB * NN;

  dim3 blk(256);
  dim3 gg(512);  // flat grid, XCD-swizzled inside
  gemm_e_stats<<<gg, blk, 0, stream>>>(px, hx, p_mask, h_mask, E, rpm, rps, cpm, cps);
  merge_stats<<<dim3(NB, 2), dim3(512), 0, stream>>>(rpm, rps, cpm, cps,
                                                     rmaxv, rinvv, cmaxv, cinvv);
  gemm_wp<<<gg, blk, 0, stream>>>(E, hx, px, h_mask, rmaxv, rinvv, out);
  gemm_wh<<<gg, blk, 0, stream>>>(E, px, hx, p_mask, cmaxv, cinvv,
                                  out + (size_t)NB * NN * ROWC);
}

// Round 5
// 228.866 us; speedup vs baseline: 1.1338x; 1.1338x over previous
//
#include <hip/hip_runtime.h>
#include <math.h>

#define NB 32
#define NN 512
#define ROWC 2048ull

typedef __attribute__((ext_vector_type(8))) short bf16x8;
typedef __attribute__((ext_vector_type(4))) float f32x4;

__device__ __forceinline__ unsigned int fbits(float f) {
  union { float f; unsigned int u; } v; v.f = f; return v.u;
}
__device__ __forceinline__ float bcast(unsigned int u) {
  union { unsigned int u; float f; } v; v.u = u; return v.f;
}
// round-to-nearest-even bf16, returned in low 16 bits
__device__ __forceinline__ unsigned int bf16_rne(float f) {
  unsigned int b = fbits(f);
  return (b + 0x7FFFu + ((b >> 16) & 1u)) >> 16;
}

// Fragment-ordered LDS address for a 128(row)x64(k) bf16 tile.
// Region (khalf, blk) holds a 16x32 MFMA fragment: lane = (row&15)+16*k8,
// element j = k&7 at +j*2. XOR swizzle on byte[6:4] keeps staged writes
// conflict-free; reads are a bijection within each 1KB region.
__device__ __forceinline__ int frag_byte(int blk, int lane, int khalf) {
  int base = ((((khalf << 3) + blk) << 6) + lane) << 4;
  int swz = (blk ^ (lane >> 4) ^ (khalf << 2)) & 7;
  return base ^ (swz << 4);
}

// --- Kernel 1: e = px.hx^T (split-bf16 MFMA) + masked row/col softmax stats -
__global__ __launch_bounds__(256) void gemm_e_stats(
    const float* __restrict__ px, const float* __restrict__ hx,
    const int* __restrict__ p_mask, const int* __restrict__ h_mask,
    float* __restrict__ e,
    float* __restrict__ rpm, float* __restrict__ rps,
    float* __restrict__ cpm, float* __restrict__ cps) {
  __shared__ union {
    struct { char Ah[16384]; char Al[16384]; char Bh[16384]; char Bl[16384]; } s;
    float ep[64][132];
  } u;
  __shared__ int pmk[128], hmk[128];
  __shared__ float st_m[2][128], st_s[2][128], sc_m[2][128], sc_s[2][128];
  const int b = blockIdx.z;
  const float* A = px + (size_t)b * NN * NN;
  const float* B = hx + (size_t)b * NN * NN;
  float* C = e + (size_t)b * NN * NN;
  const int row0 = blockIdx.y * 128, col0 = blockIdx.x * 128;
  const int t = threadIdx.x;
  const int l = t & 63, w = t >> 6;
  const int wr = w >> 1, wc = w & 1;
  const int g = l >> 4, li = l & 15;

  if (t < 128) pmk[t] = p_mask[(size_t)b * NN + row0 + t];
  else hmk[t - 128] = h_mask[(size_t)b * NN + col0 + (t - 128)];

  f32x4 acc[4][4];
#pragma unroll
  for (int i = 0; i < 4; ++i)
#pragma unroll
    for (int j = 0; j < 4; ++j)
#pragma unroll
      for (int r = 0; r < 4; ++r) acc[i][j][r] = 0.f;

  // precomputed per-iteration row/col for staging
  for (int k0 = 0; k0 < NN; k0 += 64) {
    // ---- batch-issue all global loads first (A then B), convert after ----
    float4 fa[8], fb[8];
#pragma unroll
    for (int i = 0; i < 8; ++i) {
      int idx = i * 256 + t;
      fa[i] = *(const float4*)&A[(size_t)(row0 + (idx >> 4)) * NN + k0 + ((idx & 15) << 2)];
    }
#pragma unroll
    for (int i = 0; i < 8; ++i) {
      int idx = i * 256 + t;
      fb[i] = *(const float4*)&B[(size_t)(col0 + (idx >> 4)) * NN + k0 + ((idx & 15) << 2)];
    }
    // ---- convert + direct LDS writes (addrspace-inferable member access) --
#pragma unroll
    for (int i = 0; i < 8; ++i) {
      int idx = i * 256 + t;
      int r = idx >> 4, k = (idx & 15) << 2;
      float4 f = fa[i];
      unsigned int b0 = fbits(f.x), b1 = fbits(f.y), b2 = fbits(f.z), b3 = fbits(f.w);
      unsigned int h01 = (b0 >> 16) | (b1 & 0xFFFF0000u);
      unsigned int h23 = (b2 >> 16) | (b3 & 0xFFFF0000u);
      float r0 = f.x - bcast(b0 & 0xFFFF0000u);
      float r1 = f.y - bcast(b1 & 0xFFFF0000u);
      float r2 = f.z - bcast(b2 & 0xFFFF0000u);
      float r3 = f.w - bcast(b3 & 0xFFFF0000u);
      unsigned int l01 = (fbits(r0) >> 16) | (fbits(r1) & 0xFFFF0000u);
      unsigned int l23 = (fbits(r2) >> 16) | (fbits(r3) & 0xFFFF0000u);
      int khalf = k >> 5, k8 = (k >> 3) & 3, j = k & 7;
      int byte = frag_byte(r >> 4, (r & 15) + (k8 << 4), khalf) + (j << 1);
      *(uint2*)&u.s.Ah[byte] = make_uint2(h01, h23);
      *(uint2*)&u.s.Al[byte] = make_uint2(l01, l23);
    }
#pragma unroll
    for (int i = 0; i < 8; ++i) {
      int idx = i * 256 + t;
      int r = idx >> 4, k = (idx & 15) << 2;
      float4 f = fb[i];
      unsigned int b0 = fbits(f.x), b1 = fbits(f.y), b2 = fbits(f.z), b3 = fbits(f.w);
      unsigned int h01 = (b0 >> 16) | (b1 & 0xFFFF0000u);
      unsigned int h23 = (b2 >> 16) | (b3 & 0xFFFF0000u);
      float r0 = f.x - bcast(b0 & 0xFFFF0000u);
      float r1 = f.y - bcast(b1 & 0xFFFF0000u);
      float r2 = f.z - bcast(b2 & 0xFFFF0000u);
      float r3 = f.w - bcast(b3 & 0xFFFF0000u);
      unsigned int l01 = (fbits(r0) >> 16) | (fbits(r1) & 0xFFFF0000u);
      unsigned int l23 = (fbits(r2) >> 16) | (fbits(r3) & 0xFFFF0000u);
      int khalf = k >> 5, k8 = (k >> 3) & 3, j = k & 7;
      int byte = frag_byte(r >> 4, (r & 15) + (k8 << 4), khalf) + (j << 1);
      *(uint2*)&u.s.Bh[byte] = make_uint2(h01, h23);
      *(uint2*)&u.s.Bl[byte] = make_uint2(l01, l23);
    }
    __syncthreads();
#pragma unroll
    for (int kh = 0; kh < 2; ++kh) {
      bf16x8 ah[4], al[4], bh[4], bl[4];
#pragma unroll
      for (int i = 0; i < 4; ++i) {
        int ab = frag_byte(wr * 4 + i, l, kh);
        ah[i] = *(const bf16x8*)&u.s.Ah[ab];
        al[i] = *(const bf16x8*)&u.s.Al[ab];
        int bb = frag_byte(wc * 4 + i, l, kh);
        bh[i] = *(const bf16x8*)&u.s.Bh[bb];
        bl[i] = *(const bf16x8*)&u.s.Bl[bb];
      }
#pragma unroll
      for (int i = 0; i < 4; ++i)
#pragma unroll
        for (int j = 0; j < 4; ++j) {
          acc[i][j] = __builtin_amdgcn_mfma_f32_16x16x32_bf16(ah[i], bh[j], acc[i][j], 0, 0, 0);
          acc[i][j] = __builtin_amdgcn_mfma_f32_16x16x32_bf16(ah[i], bl[j], acc[i][j], 0, 0, 0);
          acc[i][j] = __builtin_amdgcn_mfma_f32_16x16x32_bf16(al[i], bh[j], acc[i][j], 0, 0, 0);
        }
    }
    __syncthreads();
  }

  // ---- row stats (softmax over h): max & sum(exp) over this block's 128 cols
#pragma unroll
  for (int i = 0; i < 4; ++i)
#pragma unroll
    for (int r = 0; r < 4; ++r) {
      float v[4];
      float m = -INFINITY;
#pragma unroll
      for (int j = 0; j < 4; ++j) {
        v[j] = hmk[wc * 64 + j * 16 + li] ? -INFINITY : acc[i][j][r];
        m = fmaxf(m, v[j]);
      }
#pragma unroll
      for (int o = 1; o < 16; o <<= 1) m = fmaxf(m, __shfl_xor(m, o));
      float s = 0.f;
#pragma unroll
      for (int j = 0; j < 4; ++j) s += (v[j] == -INFINITY) ? 0.f : __expf(v[j] - m);
#pragma unroll
      for (int o = 1; o < 16; o <<= 1) s += __shfl_xor(s, o);
      if (li == 0) {
        st_m[wc][wr * 64 + i * 16 + g * 4 + r] = m;
        st_s[wc][wr * 64 + i * 16 + g * 4 + r] = s;
      }
    }

  // ---- col stats (softmax over p): max & sum(exp) over this block's 128 rows
#pragma unroll
  for (int j = 0; j < 4; ++j) {
    float v[16];
    float m = -INFINITY;
#pragma unroll
    for (int i = 0; i < 4; ++i)
#pragma unroll
      for (int r = 0; r < 4; ++r) {
        float x = pmk[wr * 64 + i * 16 + g * 4 + r] ? -INFINITY : acc[i][j][r];
        v[i * 4 + r] = x;
        m = fmaxf(m, x);
      }
    m = fmaxf(m, __shfl_xor(m, 16));
    m = fmaxf(m, __shfl_xor(m, 32));
    float s = 0.f;
#pragma unroll
    for (int q = 0; q < 16; ++q) s += (v[q] == -INFINITY) ? 0.f : __expf(v[q] - m);
    s += __shfl_xor(s, 16);
    s += __shfl_xor(s, 32);
    if (g == 0) {
      sc_m[wr][wc * 64 + j * 16 + li] = m;
      sc_s[wr][wc * 64 + j * 16 + li] = s;
    }
  }
  __syncthreads();

  if (t < 128) {
    float m0 = st_m[0][t], m1 = st_m[1][t];
    float s0 = st_s[0][t], s1 = st_s[1][t];
    float m = fmaxf(m0, m1);
    float s = 0.f;
    if (s0 > 0.f) s += s0 * __expf(m0 - m);
    if (s1 > 0.f) s += s1 * __expf(m1 - m);
    rpm[((size_t)b * 4 + blockIdx.x) * NN + row0 + t] = m;
    rps[((size_t)b * 4 + blockIdx.x) * NN + row0 + t] = s;
  } else {
    int c = t - 128;
    float m0 = sc_m[0][c], m1 = sc_m[1][c];
    float s0 = sc_s[0][c], s1 = sc_s[1][c];
    float m = fmaxf(m0, m1);
    float s = 0.f;
    if (s0 > 0.f) s += s0 * __expf(m0 - m);
    if (s1 > 0.f) s += s1 * __expf(m1 - m);
    cpm[((size_t)b * 4 + blockIdx.y) * NN + col0 + c] = m;
    cps[((size_t)b * 4 + blockIdx.y) * NN + col0 + c] = s;
  }

  // ---- E write via LDS bounce -> coalesced float4 stores ----
#pragma unroll
  for (int pass = 0; pass < 2; ++pass) {
    __syncthreads();
    if (wr == pass) {
#pragma unroll
      for (int i = 0; i < 4; ++i)
#pragma unroll
        for (int j = 0; j < 4; ++j)
#pragma unroll
          for (int r = 0; r < 4; ++r)
            u.ep[i * 16 + g * 4 + r][wc * 64 + j * 16 + li] = acc[i][j][r];
    }
    __syncthreads();
#pragma unroll
    for (int i = 0; i < 8; ++i) {
      int idx = i * 256 + t;
      int r = idx >> 5, c4 = idx & 31;
      int grow = row0 + pass * 64 + r;
      float4 v = *(const float4*)&u.ep[r][c4 * 4];
      *(float4*)&C[(size_t)grow * NN + col0 + c4 * 4] = v;
    }
  }
}

// --- Kernel 2: merge 4 partials per row/col (online-softmax merge) ---------
__global__ __launch_bounds__(512) void merge_stats(
    const float* __restrict__ rpm, const float* __restrict__ rps,
    const float* __restrict__ cpm, const float* __restrict__ cps,
    float* __restrict__ rmax, float* __restrict__ rinv,
    float* __restrict__ cmax, float* __restrict__ cinv) {
  const int b = blockIdx.x;
  const int t = threadIdx.x;
  const float* pm = blockIdx.y == 0 ? rpm : cpm;
  const float* ps = blockIdx.y == 0 ? rps : cps;
  float* fm = blockIdx.y == 0 ? rmax : cmax;
  float* fi = blockIdx.y == 0 ? rinv : cinv;
  float mj[4], sj[4];
  float m = -INFINITY;
#pragma unroll
  for (int j = 0; j < 4; ++j) {
    mj[j] = pm[((size_t)b * 4 + j) * NN + t];
    sj[j] = ps[((size_t)b * 4 + j) * NN + t];
    m = fmaxf(m, mj[j]);
  }
  float s = 0.f;
#pragma unroll
  for (int j = 0; j < 4; ++j)
    if (sj[j] > 0.f) s += sj[j] * __expf(mj[j] - m);
  fm[(size_t)b * NN + t] = m;
  fi[(size_t)b * NN + t] = 1.0f / s;
}

// --- Kernel 3: m_p : px_hat = softmax_h(e) @ hx, weights computed on the fly
__global__ __launch_bounds__(256) void gemm_wp(
    const float* __restrict__ E, const float* __restrict__ hxg,
    const float* __restrict__ pxg, const int* __restrict__ h_mask,
    const float* __restrict__ rmax, const float* __restrict__ rinv,
    float* __restrict__ outg) {
  __shared__ union {
    struct { char A[16384]; char B[16384]; } s;
    float ep[64][132];
  } u;
  const int b = blockIdx.z;
  const float* Eb = E + (size_t)b * NN * NN;
  const float* B = hxg + (size_t)b * NN * NN;
  const float* X = pxg + (size_t)b * NN * NN;
  const int* hm = h_mask + (size_t)b * NN;
  const float* rmx = rmax + (size_t)b * NN;
  const float* rin = rinv + (size_t)b * NN;
  float* out = outg + (size_t)b * NN * ROWC;
  const int row0 = blockIdx.y * 128, col0 = blockIdx.x * 128;
  const int t = threadIdx.x;
  const int l = t & 63, w = t >> 6;
  const int wr = w >> 1, wc = w & 1;

  float rmv[8];
#pragma unroll
  for (int i = 0; i < 8; ++i) rmv[i] = rmx[row0 + ((i * 256 + t) >> 4)];

  f32x4 acc[4][4];
#pragma unroll
  for (int i = 0; i < 4; ++i)
#pragma unroll
    for (int j = 0; j < 4; ++j)
#pragma unroll
      for (int r = 0; r < 4; ++r) acc[i][j][r] = 0.f;

  for (int k0 = 0; k0 < NN; k0 += 64) {
    // stage A: w = exp(e - rowmax), masked h -> 0, to bf16 frag order
#pragma unroll
    for (int i = 0; i < 8; ++i) {
      int idx = i * 256 + t;
      int r = idx >> 4, c4 = idx & 15, k = c4 << 2;
      float4 f = *(const float4*)&Eb[(size_t)(row0 + r) * NN + k0 + k];
      int4 m4 = *(const int4*)&hm[k0 + k];
      float w0 = m4.x ? 0.f : __expf(f.x - rmv[i]);
      float w1 = m4.y ? 0.f : __expf(f.y - rmv[i]);
      float w2 = m4.z ? 0.f : __expf(f.z - rmv[i]);
      float w3 = m4.w ? 0.f : __expf(f.w - rmv[i]);
      unsigned int p01 = bf16_rne(w0) | (bf16_rne(w1) << 16);
      unsigned int p23 = bf16_rne(w2) | (bf16_rne(w3) << 16);
      int khalf = k >> 5, k8 = (k >> 3) & 3, j = k & 7;
      int byte = frag_byte(r >> 4, (r & 15) + (k8 << 4), khalf) + (j << 1);
      *(uint2*)&u.s.A[byte] = make_uint2(p01, p23);
    }
    // stage B: hx fp32 [k][n] -> bf16, transposed into frag order (k-pairs)
#pragma unroll
    for (int i = 0; i < 4; ++i) {
      int idx = i * 256 + t;
      int kp = idx >> 5, nq = idx & 31;
      int k = kp << 1, n = nq << 2;
      const float* p0 = &B[(size_t)(k0 + k) * NN + col0 + n];
      float4 f0 = *(const float4*)p0;
      float4 f1 = *(const float4*)(p0 + NN);
      int khalf = k >> 5, k8 = (k >> 3) & 3, j = k & 7;
      float fa0[4] = {f0.x, f0.y, f0.z, f0.w};
      float fa1[4] = {f1.x, f1.y, f1.z, f1.w};
#pragma unroll
      for (int c = 0; c < 4; ++c) {
        unsigned int pk = bf16_rne(fa0[c]) | (bf16_rne(fa1[c]) << 16);
        int nn2 = n + c;
        int byte = frag_byte(nn2 >> 4, (nn2 & 15) + (k8 << 4), khalf) + (j << 1);
        *(unsigned int*)&u.s.B[byte] = pk;
      }
    }
    __syncthreads();
#pragma unroll
    for (int kh = 0; kh < 2; ++kh) {
      bf16x8 av[4], bv[4];
#pragma unroll
      for (int i = 0; i < 4; ++i) {
        av[i] = *(const bf16x8*)&u.s.A[frag_byte(wr * 4 + i, l, kh)];
        bv[i] = *(const bf16x8*)&u.s.B[frag_byte(wc * 4 + i, l, kh)];
      }
#pragma unroll
      for (int i = 0; i < 4; ++i)
#pragma unroll
        for (int j = 0; j < 4; ++j)
          acc[i][j] = __builtin_amdgcn_mfma_f32_16x16x32_bf16(av[i], bv[j], acc[i][j], 0, 0, 0);
    }
    __syncthreads();
  }

  const int g = l >> 4, li = l & 15;
#pragma unroll
  for (int pass = 0; pass < 2; ++pass) {
    if (wr == pass) {
#pragma unroll
      for (int i = 0; i < 4; ++i)
#pragma unroll
        for (int j = 0; j < 4; ++j)
#pragma unroll
          for (int r = 0; r < 4; ++r)
            u.ep[i * 16 + g * 4 + r][wc * 64 + j * 16 + li] = acc[i][j][r];
    }
    __syncthreads();
#pragma unroll
    for (int i = 0; i < 8; ++i) {
      int idx = i * 256 + t;
      int r = idx >> 5, c4 = idx & 31;
      int grow = row0 + pass * 64 + r;
      float ri = rin[grow];
      float4 ph = *(const float4*)&u.ep[r][c4 * 4];
      ph.x *= ri; ph.y *= ri; ph.z *= ri; ph.w *= ri;
      float4 xv = *(const float4*)&X[(size_t)grow * NN + col0 + c4 * 4];
      size_t base = (size_t)grow * ROWC + col0 + c4 * 4;
      *(float4*)&out[base] = xv;
      *(float4*)&out[base + 512] = ph;
      float4 df = {xv.x - ph.x, xv.y - ph.y, xv.z - ph.z, xv.w - ph.w};
      *(float4*)&out[base + 1024] = df;
      float4 pr = {xv.x * ph.x, xv.y * ph.y, xv.z * ph.z, xv.w * ph.w};
      *(float4*)&out[base + 1536] = pr;
    }
    __syncthreads();
  }
}

// --- Kernel 4: m_h : hx_hat = softmax_p(e)^T @ px, weights on the fly ------
__global__ __launch_bounds__(256) void gemm_wh(
    const float* __restrict__ E, const float* __restrict__ pxg,
    const float* __restrict__ hxg, const int* __restrict__ p_mask,
    const float* __restrict__ cmax, const float* __restrict__ cinv,
    float* __restrict__ outg) {
  __shared__ union {
    struct { char A[16384]; char B[16384]; } s;
    float ep[64][132];
  } u;
  const int b = blockIdx.z;
  const float* Eb = E + (size_t)b * NN * NN;
  const float* B = pxg + (size_t)b * NN * NN;
  const float* X = hxg + (size_t)b * NN * NN;
  const int* pmsk = p_mask + (size_t)b * NN;
  const float* cmx = cmax + (size_t)b * NN;
  const float* cin = cinv + (size_t)b * NN;
  float* out = outg + (size_t)b * NN * ROWC;
  const int row0 = blockIdx.y * 128, col0 = blockIdx.x * 128;  // rows = h
  const int t = threadIdx.x;
  const int l = t & 63, w = t >> 6;
  const int wr = w >> 1, wc = w & 1;

  float4 cmv[4];
#pragma unroll
  for (int i = 0; i < 4; ++i) {
    int idx = i * 256 + t;
    int n = (idx & 31) << 2;
    cmv[i] = *(const float4*)&cmx[row0 + n];
  }

  f32x4 acc[4][4];
#pragma unroll
  for (int i = 0; i < 4; ++i)
#pragma unroll
    for (int j = 0; j < 4; ++j)
#pragma unroll
      for (int r = 0; r < 4; ++r) acc[i][j][r] = 0.f;

  for (int k0 = 0; k0 < NN; k0 += 64) {
    // stage A: w[h][p] = exp(e[p][h] - colmax[h]), masked p -> 0 (k-pairs)
#pragma unroll
    for (int i = 0; i < 4; ++i) {
      int idx = i * 256 + t;
      int kp = idx >> 5, nq = idx & 31;
      int k = kp << 1, n = nq << 2;
      const float* p0 = &Eb[(size_t)(k0 + k) * NN + row0 + n];
      float4 f0 = *(const float4*)p0;
      float4 f1 = *(const float4*)(p0 + NN);
      int pm0 = pmsk[k0 + k], pm1 = pmsk[k0 + k + 1];
      float fa0[4] = {f0.x, f0.y, f0.z, f0.w};
      float fa1[4] = {f1.x, f1.y, f1.z, f1.w};
      float cma[4] = {cmv[i].x, cmv[i].y, cmv[i].z, cmv[i].w};
      int khalf = k >> 5, k8 = (k >> 3) & 3, j = k & 7;
#pragma unroll
      for (int c = 0; c < 4; ++c) {
        float w0 = pm0 ? 0.f : __expf(fa0[c] - cma[c]);
        float w1 = pm1 ? 0.f : __expf(fa1[c] - cma[c]);
        unsigned int pk = bf16_rne(w0) | (bf16_rne(w1) << 16);
        int nn2 = n + c;
        int byte = frag_byte(nn2 >> 4, (nn2 & 15) + (k8 << 4), khalf) + (j << 1);
        *(unsigned int*)&u.s.A[byte] = pk;
      }
    }
    // stage B: px fp32 [k][n] -> bf16 frag order (k-pairs)
#pragma unroll
    for (int i = 0; i < 4; ++i) {
      int idx = i * 256 + t;
      int kp = idx >> 5, nq = idx & 31;
      int k = kp << 1, n = nq << 2;
      const float* p0 = &B[(size_t)(k0 + k) * NN + col0 + n];
      float4 f0 = *(const float4*)p0;
      float4 f1 = *(const float4*)(p0 + NN);
      int khalf = k >> 5, k8 = (k >> 3) & 3, j = k & 7;
      float fa0[4] = {f0.x, f0.y, f0.z, f0.w};
      float fa1[4] = {f1.x, f1.y, f1.z, f1.w};
#pragma unroll
      for (int c = 0; c < 4; ++c) {
        unsigned int pk = bf16_rne(fa0[c]) | (bf16_rne(fa1[c]) << 16);
        int nn2 = n + c;
        int byte = frag_byte(nn2 >> 4, (nn2 & 15) + (k8 << 4), khalf) + (j << 1);
        *(unsigned int*)&u.s.B[byte] = pk;
      }
    }
    __syncthreads();
#pragma unroll
    for (int kh = 0; kh < 2; ++kh) {
      bf16x8 av[4], bv[4];
#pragma unroll
      for (int i = 0; i < 4; ++i) {
        av[i] = *(const bf16x8*)&u.s.A[frag_byte(wr * 4 + i, l, kh)];
        bv[i] = *(const bf16x8*)&u.s.B[frag_byte(wc * 4 + i, l, kh)];
      }
#pragma unroll
      for (int i = 0; i < 4; ++i)
#pragma unroll
        for (int j = 0; j < 4; ++j)
          acc[i][j] = __builtin_amdgcn_mfma_f32_16x16x32_bf16(av[i], bv[j], acc[i][j], 0, 0, 0);
    }
    __syncthreads();
  }

  const int g = l >> 4, li = l & 15;
#pragma unroll
  for (int pass = 0; pass < 2; ++pass) {
    if (wr == pass) {
#pragma unroll
      for (int i = 0; i < 4; ++i)
#pragma unroll
        for (int j = 0; j < 4; ++j)
#pragma unroll
          for (int r = 0; r < 4; ++r)
            u.ep[i * 16 + g * 4 + r][wc * 64 + j * 16 + li] = acc[i][j][r];
    }
    __syncthreads();
#pragma unroll
    for (int i = 0; i < 8; ++i) {
      int idx = i * 256 + t;
      int r = idx >> 5, c4 = idx & 31;
      int grow = row0 + pass * 64 + r;  // h
      float ci = cin[grow];
      float4 hh = *(const float4*)&u.ep[r][c4 * 4];
      hh.x *= ci; hh.y *= ci; hh.z *= ci; hh.w *= ci;
      float4 xv = *(const float4*)&X[(size_t)grow * NN + col0 + c4 * 4];
      size_t base = (size_t)grow * ROWC + col0 + c4 * 4;
      *(float4*)&out[base] = xv;
      *(float4*)&out[base + 512] = hh;
      float4 df = {xv.x - hh.x, xv.y - hh.y, xv.z - hh.z, xv.w - hh.w};
      *(float4*)&out[base + 1024] = df;
      float4 pr = {xv.x * hh.x, xv.y * hh.y, xv.z * hh.z, xv.w * hh.w};
      *(float4*)&out[base + 1536] = pr;
    }
    __syncthreads();
  }
}

extern "C" void kernel_launch(void* const* d_in, const int* in_sizes, int n_in,
                              void* d_out, int out_size, void* d_ws, size_t ws_size,
                              hipStream_t stream) {
  const float* px = (const float*)d_in[0];
  const float* hx = (const float*)d_in[1];
  const int* p_mask = (const int*)d_in[2];
  const int* h_mask = (const int*)d_in[3];
  float* out = (float*)d_out;

  float* E = (float*)d_ws;                         // 33.5 MB fp32
  float* rpm = E + (size_t)NB * NN * NN;           // [B][4][NN] partial row max
  float* rps = rpm + (size_t)NB * 4 * NN;
  float* cpm = rps + (size_t)NB * 4 * NN;
  float* cps = cpm + (size_t)NB * 4 * NN;
  float* rmaxv = cps + (size_t)NB * 4 * NN;        // [B][NN] finals
  float* rinvv = rmaxv + (size_t)NB * NN;
  float* cmaxv = rinvv + (size_t)NB * NN;
  float* cinvv = cmaxv + (size_t)NB * NN;

  dim3 blk(256);
  dim3 gg(4, 4, NB);
  gemm_e_stats<<<gg, blk, 0, stream>>>(px, hx, p_mask, h_mask, E, rpm, rps, cpm, cps);
  merge_stats<<<dim3(NB, 2), dim3(512), 0, stream>>>(rpm, rps, cpm, cps,
                                                     rmaxv, rinvv, cmaxv, cinvv);
  gemm_wp<<<gg, blk, 0, stream>>>(E, hx, px, h_mask, rmaxv, rinvv, out);
  gemm_wh<<<gg, blk, 0, stream>>>(E, px, hx, p_mask, cmaxv, cinvv,
                                  out + (size_t)NB * NN * ROWC);
}